// Round 9
// baseline (403.325 us; speedup 1.0000x reference)
//
#include <hip/hip_runtime.h>
#include <stdint.h>

// ---------------------------------------------------------------------------
// torch-ngp hashgrid encode (16 levels, dim 2) + 32->64->8 ReLU MLP, 8-corner
// trilinear blend.  One thread per (point, outer corner); 8 threads/point are
// consecutive lanes -> shuffle reduction + coalesced store.
//
// R9 vs R8 (330us; VALUBusy 56%, VGPR 36, occ 61%):  R8 proved the kernel is
// latency-chain bound (cutting 54us of VALU time moved dur by 5us).  At
// VGPR=36 the compiler kept only ~1 level's gathers in flight.  R9 makes the
// memory pipeline explicit:
//  * each level split into issue (idx calc + 8 loads into a reg buffer, keep
//    fracs) and consume (weights + fmas) -- identical arithmetic/order.
//  * 3 ping-pong buffers: issue L0,L1,L2; then {consume Li, issue Li+3}.
//    Every consume waits with 16 later loads still in flight (3x depth).
//  * __launch_bounds__(256,5): VGPR cap 102 (est. ~92 live).  5 blocks/CU =
//    62.5% theo = same occupancy R8 measured -> pure ILP gain.
//  * feats packed to half2 per level (fp[16], 16 regs) feeding R8's fdot2 MLP.
// Tripwires: WRITE_SIZE must stay 8192KB (no spills); absmax 0.00195.
// ---------------------------------------------------------------------------

#define BLK 256
#define R15 513

typedef _Float16 half2v __attribute__((ext_vector_type(2)));

// ---- level issue: compute indices, launch 8 table loads, keep fracs --------
template <int R, int H, int O>
__device__ __forceinline__ void lin_issue(float xcx, float xcy, float xcz,
                                          const float2* __restrict__ tab,
                                          float2 v[8], float& frx, float& fry, float& frz) {
    const float Rf = (float)R;
    // replicate reference op order: pos = x*R + 0.5 (no fma contraction)
    float px = __fadd_rn(__fmul_rn(xcx, Rf), 0.5f);
    float py = __fadd_rn(__fmul_rn(xcy, Rf), 0.5f);
    float pz = __fadd_rn(__fmul_rn(xcz, Rf), 0.5f);
    float fpx = floorf(px), fpy = floorf(py), fpz = floorf(pz);
    frx = px - fpx; fry = py - fpy; frz = pz - fpz;
    int gx = (int)fpx, gy = (int)fpy, gz = (int)fpz;
    const int R1 = R + 1;
    int xt[2] = {gx, gx + 1};
    int yt[2] = {gy * R1, gy * R1 + R1};
    int zt[2] = {gz * R1 * R1, gz * R1 * R1 + R1 * R1};
#pragma unroll
    for (int c = 0; c < 8; ++c) {  // corner order (x,y,z) = bits (2,1,0)
        const int ox = (c >> 2) & 1, oy = (c >> 1) & 1, oz = c & 1;
        int id  = xt[ox] + yt[oy] + zt[oz];
        int idx = (int)((uint32_t)id % (uint32_t)H);  // identity on tight grids, kept for parity
        v[c] = tab[O + idx];
    }
}

template <int RI, int O>
__device__ __forceinline__ void hash_issue(float xcx, float xcy, float xcz,
                                           const float2* __restrict__ tab,
                                           float2 v[8], float& frx, float& fry, float& frz) {
    const float Rf = (float)RI;
    float px = __fadd_rn(__fmul_rn(xcx, Rf), 0.5f);
    float py = __fadd_rn(__fmul_rn(xcy, Rf), 0.5f);
    float pz = __fadd_rn(__fmul_rn(xcz, Rf), 0.5f);
    float fpx = floorf(px), fpy = floorf(py), fpz = floorf(pz);
    frx = px - fpx; fry = py - fpy; frz = pz - fpz;
    uint32_t gx = (uint32_t)(int)fpx, gy = (uint32_t)(int)fpy, gz = (uint32_t)(int)fpz;
    // instant-NGP fast_hash primes {1, 2654435761, 805459861}; CSE the muls
    uint32_t xt[2] = {gx, gx + 1u};
    uint32_t yt[2] = {gy * 2654435761u, gy * 2654435761u + 2654435761u};
    uint32_t zt[2] = {gz * 805459861u,  gz * 805459861u  + 805459861u};
#pragma unroll
    for (int c = 0; c < 8; ++c) {
        const int ox = (c >> 2) & 1, oy = (c >> 1) & 1, oz = c & 1;
        uint32_t idx = (xt[ox] ^ yt[oy] ^ zt[oz]) & 524287u;
        v[c] = tab[O + (int)idx];
    }
}

// ---- level consume: trilinear weights + fmas (identical order to R2/R8) ----
__device__ __forceinline__ void enc_consume(const float2 v[8], float frx, float fry, float frz,
                                            float& f0, float& f1) {
    float wx[2] = {1.f - frx, frx};
    float wy[2] = {1.f - fry, fry};
    float wz[2] = {1.f - frz, frz};
    float a0 = 0.f, a1 = 0.f;
#pragma unroll
    for (int c = 0; c < 8; ++c) {
        const int ox = (c >> 2) & 1, oy = (c >> 1) & 1, oz = c & 1;
        float w = wx[ox] * wy[oy] * wz[oz];
        a0 = fmaf(w, v[c].x, a0);
        a1 = fmaf(w, v[c].y, a1);
    }
    f0 = a0; f1 = a1;
}

// ---- prep: pack weights into half2 pairs over the reduction axis ----------
// ws[0..1023]   : w1p[ip*64 + k] = {w1[2ip][k], w1[2ip+1][k]}   (ip<16, k<64)
// ws[1024..1279]: w2p[kp*8  + j] = {w2[2kp][j], w2[2kp+1][j]}   (kp<32, j<8)
__global__ void pack_weights(const float* __restrict__ w1,
                             const float* __restrict__ w2,
                             uint32_t* __restrict__ ws) {
    int idx = blockIdx.x * blockDim.x + threadIdx.x;
    float a, b;
    if (idx < 1024) {
        int ip = idx >> 6, k = idx & 63;
        a = w1[(2 * ip) * 64 + k];
        b = w1[(2 * ip + 1) * 64 + k];
    } else if (idx < 1280) {
        int r = idx - 1024;
        int kp = r >> 3, j = r & 7;
        a = w2[(2 * kp) * 8 + j];
        b = w2[(2 * kp + 1) * 8 + j];
    } else {
        return;
    }
    half2v h = {(_Float16)a, (_Float16)b};  // RTE converts
    ws[idx] = *(const uint32_t*)&h;
}

__global__ __launch_bounds__(BLK, 5)
void grid_fused(const float* __restrict__ xyz, const float* __restrict__ bound,
                const float* __restrict__ table, const uint32_t* __restrict__ wsp,
                float* __restrict__ out, int N) {
    const int tid = threadIdx.x;
    const int t = blockIdx.x * BLK + tid;
    const int p = t >> 3;
    const int a = t & 7;
    if (p >= N) return;

    const float2* tab = (const float2*)table;

    const float b = bound[0];
    float X = xyz[3 * p + 0], Y = xyz[3 * p + 1], Z = xyz[3 * p + 2];
    // x = (xyz + bound) / (2*bound); coords = x * 512
    float cx = ((X + b) / (2.0f * b)) * 512.0f;
    float cy = ((Y + b) / (2.0f * b)) * 512.0f;
    float cz = ((Z + b) / (2.0f * b)) * 512.0f;
    float c0x = fmaxf(fminf(floorf(cx), 511.f), 0.f);
    float c0y = fmaxf(fminf(floorf(cy), 511.f), 0.f);
    float c0z = fmaxf(fminf(floorf(cz), 511.f), 0.f);
    float uu = cx - c0x, vv = cy - c0y, wwf = cz - c0z;  // outer trilinear fracs

    const int ax = (a >> 2) & 1, ay = (a >> 1) & 1, az = a & 1;  // CORNERS order
    // encode-space coordinate of this outer corner: (c0+a)/512, exact
    float xcx = (c0x + (float)ax) * (1.0f / 512.0f);
    float xcy = (c0y + (float)ay) * (1.0f / 512.0f);
    float xcz = (c0z + (float)az) * (1.0f / 512.0f);

    // ---- 16 levels, 3-deep issue/consume pipeline -> fp[16] half2 feats ----
    // Buffers a/b/c rotate; every consume waits with 16 later loads in flight.
    half2v fp[16];
    float2 va[8], vb[8], vc[8];
    float fxa, fya, fza, fxb, fyb, fzb, fxc, fyc, fzc;
    float f0, f1;

#define CONS(i, V, FX, FY, FZ) \
    { enc_consume(V, FX, FY, FZ, f0, f1); fp[i] = (half2v){(_Float16)f0, (_Float16)f1}; }

    lin_issue<16,   4920,      0>(xcx, xcy, xcz, tab, va, fxa, fya, fza);
    lin_issue<21,  10648,   4920>(xcx, xcy, xcz, tab, vb, fxb, fyb, fzb);
    lin_issue<26,  19688,  15568>(xcx, xcy, xcz, tab, vc, fxc, fyc, fzc);
    CONS(0, va, fxa, fya, fza);
    lin_issue<33,  39304,  35256>(xcx, xcy, xcz, tab, va, fxa, fya, fza);
    CONS(1, vb, fxb, fyb, fzb);
    lin_issue<41,  74088,  74560>(xcx, xcy, xcz, tab, vb, fxb, fyb, fzb);
    CONS(2, vc, fxc, fyc, fzc);
    lin_issue<51, 140608, 148648>(xcx, xcy, xcz, tab, vc, fxc, fyc, fzc);
    CONS(3, va, fxa, fya, fza);
    lin_issue<65, 287496, 289256>(xcx, xcy, xcz, tab, va, fxa, fya, fza);
    CONS(4, vb, fxb, fyb, fzb);
    hash_issue< 81,  576752>(xcx, xcy, xcz, tab, vb, fxb, fyb, fzb);
    CONS(5, vc, fxc, fyc, fzc);
    hash_issue<102, 1101040>(xcx, xcy, xcz, tab, vc, fxc, fyc, fzc);
    CONS(6, va, fxa, fya, fza);
    hash_issue<129, 1625328>(xcx, xcy, xcz, tab, va, fxa, fya, fza);
    CONS(7, vb, fxb, fyb, fzb);
    hash_issue<162, 2149616>(xcx, xcy, xcz, tab, vb, fxb, fyb, fzb);
    CONS(8, vc, fxc, fyc, fzc);
    hash_issue<204, 2673904>(xcx, xcy, xcz, tab, vc, fxc, fyc, fzc);
    CONS(9, va, fxa, fya, fza);
    hash_issue<257, 3198192>(xcx, xcy, xcz, tab, va, fxa, fya, fza);
    CONS(10, vb, fxb, fyb, fzb);
    hash_issue<324, 3722480>(xcx, xcy, xcz, tab, vb, fxb, fyb, fzb);
    CONS(11, vc, fxc, fyc, fzc);
    hash_issue<408, 4246768>(xcx, xcy, xcz, tab, vc, fxc, fyc, fzc);
    CONS(12, va, fxa, fya, fza);
    hash_issue<R15, 4771056>(xcx, xcy, xcz, tab, va, fxa, fya, fza);
    CONS(13, vb, fxb, fyb, fzb);
    CONS(14, vc, fxc, fyc, fzc);
    CONS(15, va, fxa, fya, fza);
#undef CONS

    const half2v* w1p = (const half2v*)wsp;          // [ip*64 + k]
    const half2v* w2p = (const half2v*)(wsp + 1024); // [kp*8 + j]

    // ---- MLP: relu(feats @ w1) @ w2 via v_dot2_f32_f16 (f32 accumulate) ----
    // weight addresses depend only on loop indices -> wave-uniform s_loads.
    float acc[8] = {0.f, 0.f, 0.f, 0.f, 0.f, 0.f, 0.f, 0.f};
#pragma unroll 1
    for (int kb = 0; kb < 64; kb += 16) {
        float h[16];
#pragma unroll
        for (int k = 0; k < 16; ++k) h[k] = 0.f;
#pragma unroll
        for (int ip = 0; ip < 16; ++ip) {
#pragma unroll
            for (int k = 0; k < 16; ++k)
                h[k] = __builtin_amdgcn_fdot2(fp[ip], w1p[ip * 64 + kb + k], h[k], false);
        }
        // relu + pack hidden pairs, then layer-2 dot2s for this chunk
        half2v hp[8];
#pragma unroll
        for (int kp = 0; kp < 8; ++kp)
            hp[kp] = (half2v){(_Float16)fmaxf(h[2 * kp], 0.f),
                              (_Float16)fmaxf(h[2 * kp + 1], 0.f)};
#pragma unroll
        for (int kp = 0; kp < 8; ++kp) {
            const int kpg = (kb >> 1) + kp;  // global hidden-pair index
#pragma unroll
            for (int j = 0; j < 8; ++j)
                acc[j] = __builtin_amdgcn_fdot2(hp[kp], w2p[kpg * 8 + j], acc[j], false);
        }
    }

    // ---- outer trilinear weight + 8-lane reduction --------------------------
    float wt = (ax ? uu : 1.f - uu) * (ay ? vv : 1.f - vv) * (az ? wwf : 1.f - wwf);
#pragma unroll
    for (int j = 0; j < 8; ++j) {
        float v = acc[j] * wt;
        v += __shfl_xor(v, 1);
        v += __shfl_xor(v, 2);
        v += __shfl_xor(v, 4);
        acc[j] = v;  // all 8 lanes now hold the full sum for output j
    }
    // lane a writes output column a -> out[p*8 + a] == out[t], fully coalesced
    float r01 = (a & 1) ? acc[1] : acc[0];
    float r23 = (a & 1) ? acc[3] : acc[2];
    float r45 = (a & 1) ? acc[5] : acc[4];
    float r67 = (a & 1) ? acc[7] : acc[6];
    float r03 = (a & 2) ? r23 : r01;
    float r47 = (a & 2) ? r67 : r45;
    float r   = (a & 4) ? r47 : r03;
    out[t] = r;
}

extern "C" void kernel_launch(void* const* d_in, const int* in_sizes, int n_in,
                              void* d_out, int out_size, void* d_ws, size_t ws_size,
                              hipStream_t stream) {
    const float* xyz   = (const float*)d_in[0];
    const float* bound = (const float*)d_in[1];
    const float* table = (const float*)d_in[2];
    const float* w1    = (const float*)d_in[3];
    const float* w2    = (const float*)d_in[4];
    float* out = (float*)d_out;
    uint32_t* ws = (uint32_t*)d_ws;   // needs 1280 * 4 B = 5 KB

    const int N = in_sizes[0] / 3;          // 262144
    pack_weights<<<5, 256, 0, stream>>>(w1, w2, ws);

    const int threads = N * 8;              // one thread per (point, corner)
    const int blocks = (threads + BLK - 1) / BLK;
    grid_fused<<<blocks, BLK, 0, stream>>>(xyz, bound, table, ws, out, N);
}